// Round 1
// baseline (1670.047 us; speedup 1.0000x reference)
//
#include <hip/hip_runtime.h>
#include <hip/hip_fp16.h>

// Problem constants (from reference)
#define BSZ 32
#define CS_ 640
#define CT_ 768
#define NTOK 576
#define HID 64
#define ITERS 50
#define ROWS 72          // rows of M per workgroup
#define WGB 8            // workgroups per batch
#define PITCH 650        // fp16 LDS pitch for Ms (bank-conflict-free column access: 325%32=5, gcd(5,32)=1)
#define PADCOL 640       // u-pass column extent (576 real + pad of -1000)

#define LOG2_N 9.169925001442312f         // log2(576)
#define MS_SCALE 14.426950408889634f      // 10 * log2(e)   (Ms' = M/reg * log2e)
#define M_FROM_MSP 0.06931471805599453f   // ln2 / 10       (M = Ms' * this)

// Workspace layout (bytes)
#define OFF_CNT 0              // 32 counters, 64B apart  (2048 B)
#define OFF_P 2048             // partials [2][32][8][576] f32 = 1,179,648 B
#define OFF_XS 1181696         // xs_lin [32][576][64] f32 = 4,718,592 B
#define OFF_XT 5900288         // xt_lin [32][576][64] f32 = 4,718,592 B
#define OFF_SS 10618880        // scale_s [32][64] f32
#define OFF_ST 10627072        // scale_t [32][64] f32
#define OFF_WOUT 10635264      // per-wg partial outputs [256] f32

#define SMEM_BYTES 160800

// ---------------------------------------------------------------------------
// K1: xs_lin[b,n,h] = sum_c feat[b,c,n] * W[h,c] + bias[h]
// One wave owns 64 tokens (lane = token), 32 h-values in registers; W read via
// scalar loads (index is wave-uniform thanks to readfirstlane).
// ---------------------------------------------------------------------------
__global__ __launch_bounds__(128) void k1_proj(
    const float* __restrict__ feat_s, const float* __restrict__ feat_t,
    const float* __restrict__ Ws, const float* __restrict__ bs,
    const float* __restrict__ Wt, const float* __restrict__ bt,
    float* __restrict__ xs, float* __restrict__ xt)
{
    const int nblk = blockIdx.x, b = blockIdx.y, st = blockIdx.z;
    const float* feat = st ? feat_t : feat_s;
    const float* W    = st ? Wt : Ws;
    const float* bias = st ? bt : bs;
    float* out        = st ? xt : xs;
    const int C       = st ? CT_ : CS_;

    const int lane = threadIdx.x & 63;
    const int wv = __builtin_amdgcn_readfirstlane((int)(threadIdx.x >> 6));
    const int h0 = wv * 32;
    const int n = nblk * 64 + lane;

    float acc[32];
#pragma unroll
    for (int i = 0; i < 32; i++) acc[i] = 0.f;

    const float* fb = feat + (size_t)b * C * NTOK + n;
    for (int c0 = 0; c0 < C; c0 += 16) {
        float f[16];
#pragma unroll
        for (int j = 0; j < 16; j++) f[j] = fb[(size_t)(c0 + j) * NTOK];
#pragma unroll
        for (int hh = 0; hh < 32; hh++) {
            const float* wr = W + (size_t)(h0 + hh) * C + c0;
#pragma unroll
            for (int j = 0; j < 16; j++) acc[hh] = fmaf(f[j], wr[j], acc[hh]);
        }
    }
    float* orow = out + ((size_t)b * NTOK + n) * HID + h0;
#pragma unroll
    for (int hh = 0; hh < 32; hh += 4) {
        float4 v = make_float4(acc[hh] + bias[h0 + hh],
                               acc[hh + 1] + bias[h0 + hh + 1],
                               acc[hh + 2] + bias[h0 + hh + 2],
                               acc[hh + 3] + bias[h0 + hh + 3]);
        *(float4*)(orow + hh) = v;
    }
}

// ---------------------------------------------------------------------------
// K2: column norms over the token axis; scale[b,h] = 1/max(sqrt(sum_n x^2),eps)
// ---------------------------------------------------------------------------
__global__ __launch_bounds__(1024) void k2_norm(
    const float* __restrict__ xs, const float* __restrict__ xt,
    float* __restrict__ ss, float* __restrict__ stc)
{
    const int b = blockIdx.x, st = blockIdx.y;
    const float* x = st ? xt : xs;
    float* sc = st ? stc : ss;
    const int h = threadIdx.x & 63, ng = threadIdx.x >> 6;
    const float* xb = x + (size_t)b * NTOK * HID;
    float a = 0.f;
    for (int n1 = ng; n1 < NTOK; n1 += 16) {
        float v = xb[n1 * HID + h];
        a = fmaf(v, v, a);
    }
    __shared__ float red[16][64];
    red[ng][h] = a;
    __syncthreads();
    if (threadIdx.x < 64) {
        float s = 0.f;
#pragma unroll
        for (int g = 0; g < 16; g++) s += red[g][threadIdx.x];
        sc[b * 64 + threadIdx.x] = 1.0f / fmaxf(sqrtf(s), 1e-12f);
    }
}

// ---------------------------------------------------------------------------
// K4: persistent Sinkhorn. 256 wgs (1/CU), wg = (batch, 72-row slice).
// M slice lives in LDS as fp16 (Ms' = M*10*log2e). One device barrier per iter.
// ---------------------------------------------------------------------------
__global__ __launch_bounds__(1024) void k4_sinkhorn(
    const float* __restrict__ xs, const float* __restrict__ xt,
    const float* __restrict__ ss, const float* __restrict__ stc,
    float* __restrict__ P, int* __restrict__ counters, float* __restrict__ wgout)
{
    extern __shared__ char smem[];
    __half* Ms  = (__half*)smem;                       // 72*650 fp16 = 93600 B
    float* xs_l = (float*)(smem + 93600);              // 72*68
    float* xt_l = xs_l + ROWS * 68;                    // 144*68
    float* sqs  = xt_l + 144 * 68;                     // 72
    float* sqt  = sqs + ROWS;                          // 144
    float* u_l  = sqt + 144;                           // 72
    float* v_l  = u_l + ROWS;                          // 640
    float* vtmp = v_l + PADCOL;                        // 2*288*2 = 1152
    float* red  = vtmp + 1152;                         // 32

    const int tid = threadIdx.x;
    const int b = blockIdx.x >> 3, part = blockIdx.x & 7;
    const int r0 = part * ROWS;
    const int lane = tid & 63, wv = tid >> 6;

    // ---- stage scaled xs rows, init v' ----
    for (int idx = tid; idx < ROWS * HID; idx += 1024) {
        int n1 = idx >> 6, h = idx & 63;
        xs_l[n1 * 68 + h] = xs[((size_t)b * NTOK + r0 + n1) * HID + h] * ss[b * 64 + h];
    }
    for (int m = tid; m < PADCOL; m += 1024) v_l[m] = (m < NTOK) ? 0.f : -1000.f;
    __syncthreads();
    if (tid < ROWS) {
        float s = 0.f;
#pragma unroll
        for (int h = 0; h < HID; h++) { float v = xs_l[tid * 68 + h]; s = fmaf(v, v, s); }
        sqs[tid] = s;
    }

    // ---- build Ms' slice in LDS (4 tiles of 144 cols) ----
    for (int mt = 0; mt < NTOK; mt += 144) {
        __syncthreads();
        for (int idx = tid; idx < 144 * HID; idx += 1024) {
            int mm = idx >> 6, h = idx & 63;
            xt_l[mm * 68 + h] = xt[((size_t)b * NTOK + mt + mm) * HID + h] * stc[b * 64 + h];
        }
        __syncthreads();
        if (tid < 144) {
            float s = 0.f;
#pragma unroll
            for (int h = 0; h < HID; h++) { float v = xt_l[tid * 68 + h]; s = fmaf(v, v, s); }
            sqt[tid] = s;
        }
        __syncthreads();
        if (tid < 648) {
            int i = tid / 36, j = tid - (tid / 36) * 36;
            int n0 = 4 * i, m0 = 4 * j;
            float a[4][4];
#pragma unroll
            for (int r = 0; r < 4; r++)
#pragma unroll
                for (int c = 0; c < 4; c++) a[r][c] = 0.f;
            for (int h = 0; h < HID; h += 4) {
                float4 xa[4], xb4[4];
#pragma unroll
                for (int r = 0; r < 4; r++) xa[r] = *(const float4*)&xs_l[(n0 + r) * 68 + h];
#pragma unroll
                for (int c = 0; c < 4; c++) xb4[c] = *(const float4*)&xt_l[(m0 + c) * 68 + h];
#pragma unroll
                for (int r = 0; r < 4; r++)
#pragma unroll
                    for (int c = 0; c < 4; c++) {
                        a[r][c] = fmaf(xa[r].x, xb4[c].x, a[r][c]);
                        a[r][c] = fmaf(xa[r].y, xb4[c].y, a[r][c]);
                        a[r][c] = fmaf(xa[r].z, xb4[c].z, a[r][c]);
                        a[r][c] = fmaf(xa[r].w, xb4[c].w, a[r][c]);
                    }
            }
#pragma unroll
            for (int r = 0; r < 4; r++)
#pragma unroll
                for (int c = 0; c < 4; c++) {
                    float M = fmaxf(sqs[n0 + r] + sqt[m0 + c] - 2.f * a[r][c], 0.f);
                    Ms[(n0 + r) * PITCH + (mt + m0 + c)] = __float2half(M * MS_SCALE);
                }
        }
    }
    __syncthreads();
    for (int idx = tid; idx < ROWS * (PITCH - NTOK); idx += 1024) {
        int n1 = idx / (PITCH - NTOK), k = idx - n1 * (PITCH - NTOK);
        Ms[n1 * PITCH + NTOK + k] = __float2half(-1000.f);
    }
    __syncthreads();

    int* cnt = counters + b * 16;
    const size_t Pb_base = (size_t)b * WGB * NTOK;
    const size_t Ppar = (size_t)BSZ * WGB * NTOK;

    for (int it = 1; it <= ITERS; ++it) {
        if (it > 1) {
            if (tid < NTOK) {
                const float* Pp = P + Ppar * ((it - 1) & 1) + Pb_base;
                float s = 0.f;
#pragma unroll
                for (int w = 0; w < WGB; w++) s += Pp[w * NTOK + tid];
                v_l[tid] = -LOG2_N - log2f(s);
            }
            __syncthreads();
        }
        // ---- u-pass: wave per row, v' cached in registers per wave ----
        float2 vr[5];
#pragma unroll
        for (int j = 0; j < 5; j++) vr[j] = *(const float2*)&v_l[128 * j + 2 * lane];
        for (int n1 = wv; n1 < ROWS; n1 += 16) {
            const __half* row = Ms + n1 * PITCH;
            float a = 0.f;
#pragma unroll
            for (int j = 0; j < 5; j++) {
                float2 f = __half22float2(*(const __half2*)&row[128 * j + 2 * lane]);
                a += exp2f(f.x + vr[j].x);
                a += exp2f(f.y + vr[j].y);
            }
#pragma unroll
            for (int off = 32; off > 0; off >>= 1) a += __shfl_xor(a, off, 64);
            if (lane == 0) u_l[n1] = -LOG2_N - log2f(a);
        }
        __syncthreads();
        // ---- v-pass: thread owns a column pair over half the rows ----
        if (tid < NTOK) {
            int half = tid / 288, p = tid - half * 288;
            int nlo = half * 36;
            float a0 = 0.f, a1 = 0.f;
            const __half* col = Ms + 2 * p;
            for (int nn = 0; nn < 36; nn++) {
                int n1 = nlo + nn;
                float uu = u_l[n1];
                float2 f = __half22float2(*(const __half2*)&col[n1 * PITCH]);
                a0 += exp2f(f.x + uu);
                a1 += exp2f(f.y + uu);
            }
            ((float2*)vtmp)[half * 288 + p] = make_float2(a0, a1);
        }
        __syncthreads();
        if (tid < NTOK) {
            int p = tid >> 1, c = tid & 1;
            float s = vtmp[(p << 1) + c] + vtmp[576 + (p << 1) + c];
            P[Ppar * (it & 1) + Pb_base + (size_t)part * NTOK + tid] = s;
        }
        // ---- per-batch device barrier ----
        __syncthreads();
        if (tid == 0) {
            __threadfence();
            __hip_atomic_fetch_add(cnt, 1, __ATOMIC_RELEASE, __HIP_MEMORY_SCOPE_AGENT);
            const int target = WGB * it;
            while (__hip_atomic_load(cnt, __ATOMIC_RELAXED, __HIP_MEMORY_SCOPE_AGENT) < target)
                __builtin_amdgcn_s_sleep(2);
            __threadfence();
        }
        __syncthreads();
    }

    // ---- final: combine v(50), accumulate sum(T * M) over own slice ----
    if (tid < NTOK) {
        const float* Pp = P + Pb_base;  // iter 50 wrote parity 0
        float s = 0.f;
#pragma unroll
        for (int w = 0; w < WGB; w++) s += Pp[w * NTOK + tid];
        v_l[tid] = -LOG2_N - log2f(s);
    }
    __syncthreads();
    float acc = 0.f;
    for (int idx = tid; idx < ROWS * NTOK; idx += 1024) {
        int n1 = idx / NTOK, m = idx - n1 * NTOK;
        float msp = __half2float(Ms[n1 * PITCH + m]);
        float t = exp2f(msp + u_l[n1] + v_l[m]);
        acc = fmaf(t, msp, acc);
    }
#pragma unroll
    for (int off = 32; off > 0; off >>= 1) acc += __shfl_xor(acc, off, 64);
    if (lane == 0) red[wv] = acc;
    __syncthreads();
    if (tid == 0) {
        float s = 0.f;
#pragma unroll
        for (int w = 0; w < 16; w++) s += red[w];
        wgout[blockIdx.x] = s * M_FROM_MSP;
    }
}

// ---------------------------------------------------------------------------
// K5: reduce 256 wg partials -> out[0] = sum / BS
// ---------------------------------------------------------------------------
__global__ __launch_bounds__(256) void k5_reduce(const float* __restrict__ wgout,
                                                 float* __restrict__ out)
{
    const int tid = threadIdx.x;
    float v = wgout[tid];
#pragma unroll
    for (int off = 32; off > 0; off >>= 1) v += __shfl_xor(v, off, 64);
    __shared__ float r[4];
    if ((tid & 63) == 0) r[tid >> 6] = v;
    __syncthreads();
    if (tid == 0) out[0] = (r[0] + r[1] + r[2] + r[3]) * (1.0f / BSZ);
}

extern "C" void kernel_launch(void* const* d_in, const int* in_sizes, int n_in,
                              void* d_out, int out_size, void* d_ws, size_t ws_size,
                              hipStream_t stream) {
    const float* feat_s = (const float*)d_in[0];
    const float* feat_t = (const float*)d_in[1];
    const float* Ws = (const float*)d_in[2];
    const float* bs = (const float*)d_in[3];
    const float* Wt = (const float*)d_in[4];
    const float* bt = (const float*)d_in[5];

    char* ws = (char*)d_ws;
    int* counters = (int*)(ws + OFF_CNT);
    float* P      = (float*)(ws + OFF_P);
    float* xs     = (float*)(ws + OFF_XS);
    float* xt     = (float*)(ws + OFF_XT);
    float* ssc    = (float*)(ws + OFF_SS);
    float* stc    = (float*)(ws + OFF_ST);
    float* wgout  = (float*)(ws + OFF_WOUT);
    float* out = (float*)d_out;

    // barrier counters must start at 0 every launch (ws is poisoned)
    hipMemsetAsync(counters, 0, 2048, stream);

    hipLaunchKernelGGL(k1_proj, dim3(9, 32, 2), dim3(128), 0, stream,
                       feat_s, feat_t, Ws, bs, Wt, bt, xs, xt);
    hipLaunchKernelGGL(k2_norm, dim3(32, 2), dim3(1024), 0, stream, xs, xt, ssc, stc);

    // allow >64KB dynamic LDS (idempotent, host-side, capture-safe)
    (void)hipFuncSetAttribute((const void*)k4_sinkhorn,
                              hipFuncAttributeMaxDynamicSharedMemorySize, SMEM_BYTES);
    hipLaunchKernelGGL(k4_sinkhorn, dim3(256), dim3(1024), SMEM_BYTES, stream,
                       xs, xt, ssc, stc, P, counters, wgout);
    hipLaunchKernelGGL(k5_reduce, dim3(1), dim3(256), 0, stream, wgout, out);
}

// Round 2
// 1612.313 us; speedup vs baseline: 1.0358x; 1.0358x over previous
//
#include <hip/hip_runtime.h>
#include <hip/hip_fp16.h>

// Problem constants
#define BSZ 32
#define CS_ 640
#define CT_ 768
#define NTOK 576
#define HID 64
#define ITERS 50
#define WGB 12           // workgroups per batch
#define ROWS 48          // rows of M per workgroup (576/12)
#define NWG (BSZ*WGB)    // 384 total wgs: 2 per CU on >=128 CUs (LDS 75.6KB -> 2/CU)
#define MPITCH 640       // halves per Ms row (576 real + 64 pad of -1000)
#define XPITCH 68        // halves per staged x row (stride 34 dwords -> 2-way LDS, free)

#define LOG2_N 9.169925001442312f         // log2(576)
#define MS_SCALE 14.426950408889634f      // 10 * log2(e):  Ms' = M/reg * log2(e)
#define M_FROM_MSP 0.06931471805599453f   // ln2 / 10

// Workspace layout (bytes)
#define OFF_CNT 0              // 32 barrier counters, 64B apart (2048 B)
#define OFF_DONE 2048          // int
#define OFF_GSUM 2052          // float
#define OFF_SQS 2112           // sumsq [2][32][64] f32 (16384 B)
#define MEMSET_BYTES 18496
#define OFF_P 18560            // partial colsums [2][32][12][576] f32 = 1,769,472
#define OFF_XS 1788032         // xs fp16 [32][576][64] = 2,359,296
#define OFF_XT 4147328         // xt fp16 [32][576][64] = 2,359,296  (end 6.5 MB)

// LDS layout (bytes); total 75,648 -> 2 wgs/CU (151,296 <= 163,840)
#define L_MS 0                 // 48*640*2 = 61440
#define L_U 61440              // 48*4
#define L_V 61632              // 640*4
#define L_RED 64192            // 16*4
#define L_UNION 64256          // iters: vtmp 576*2*4=4608 | build: ssc(256)+stc(256)+xs_l(6528)+xt_l(4352)
#define SMEM_BYTES 75648

// ---------------------------------------------------------------------------
// K1: projection + bias -> fp16 x, plus fused per-(b,h) sum-of-squares
// (atomicAdd partials; k2 of round 1 eliminated).
// Wave = 64 tokens; 2 waves/wg cover h 0..31 / 32..63. W reads are
// wave-uniform -> scalar loads.
// ---------------------------------------------------------------------------
__global__ __launch_bounds__(128) void k1_proj(
    const float* __restrict__ feat_s, const float* __restrict__ feat_t,
    const float* __restrict__ Ws, const float* __restrict__ bs,
    const float* __restrict__ Wt, const float* __restrict__ bt,
    __half* __restrict__ xs, __half* __restrict__ xt, float* __restrict__ sumsq)
{
    const int nblk = blockIdx.x, b = blockIdx.y, st = blockIdx.z;
    const float* feat = st ? feat_t : feat_s;
    const float* W    = st ? Wt : Ws;
    const float* bias = st ? bt : bs;
    __half* out       = st ? xt : xs;
    const int C       = st ? CT_ : CS_;

    const int lane = threadIdx.x & 63;
    const int wv = __builtin_amdgcn_readfirstlane((int)(threadIdx.x >> 6));
    const int h0 = wv * 32;
    const int n = nblk * 64 + lane;

    float acc[32];
#pragma unroll
    for (int i = 0; i < 32; i++) acc[i] = 0.f;

    const float* fb = feat + (size_t)b * C * NTOK + n;
    for (int c0 = 0; c0 < C; c0 += 16) {
        float f[16];
#pragma unroll
        for (int j = 0; j < 16; j++) f[j] = fb[(size_t)(c0 + j) * NTOK];
#pragma unroll
        for (int hh = 0; hh < 32; hh++) {
            const float* wr = W + (size_t)(h0 + hh) * C + c0;
#pragma unroll
            for (int j = 0; j < 16; j++) acc[hh] = fmaf(f[j], wr[j], acc[hh]);
        }
    }
    // add bias, write fp16
#pragma unroll
    for (int hh = 0; hh < 32; hh++) acc[hh] += bias[h0 + hh];

    __half2 hp[16];
#pragma unroll
    for (int hh = 0; hh < 32; hh += 2)
        hp[hh >> 1] = __floats2half2_rn(acc[hh], acc[hh + 1]);
    float4* op = (float4*)(out + ((size_t)b * NTOK + n) * HID + h0);
#pragma unroll
    for (int q = 0; q < 4; q++) op[q] = ((const float4*)hp)[q];

    // fused sum-of-squares over tokens (for L2 norm over dim=1)
    float* sq = sumsq + (size_t)st * (BSZ * 64) + b * 64 + h0;
#pragma unroll
    for (int hh = 0; hh < 32; hh++) {
        float v2 = acc[hh] * acc[hh];
#pragma unroll
        for (int off = 32; off > 0; off >>= 1) v2 += __shfl_xor(v2, off, 64);
        if (lane == 0) atomicAdd(sq + hh, v2);
    }
}

// ---------------------------------------------------------------------------
// K4: persistent Sinkhorn. 384 wgs = 12/batch (48 rows each), 2 wgs/CU.
// blockIdx = part*32 + b  =>  all 12 parts of batch b share blockIdx%8 (XCD).
// M slice in LDS fp16 (Ms' = M*10*log2e). One device barrier per iteration.
// Final reduce fused (last wg writes d_out).
// ---------------------------------------------------------------------------
__global__ __launch_bounds__(1024, 8) void k4_sinkhorn(
    const __half* __restrict__ xsh, const __half* __restrict__ xth,
    const float* __restrict__ sumsq, float* __restrict__ P,
    int* __restrict__ counters, int* __restrict__ done,
    float* __restrict__ gsum, float* __restrict__ out)
{
    extern __shared__ char smem[];
    __half* Ms  = (__half*)(smem + L_MS);
    float* u_l  = (float*)(smem + L_U);
    float* v_l  = (float*)(smem + L_V);
    float* red  = (float*)(smem + L_RED);
    float* vtmp = (float*)(smem + L_UNION);              // iters only
    float* ssc  = (float*)(smem + L_UNION);              // build only
    float* stc  = ssc + 64;
    __half* xs_l = (__half*)(smem + L_UNION + 512);      // 48*68 halves
    __half* xt_l = xs_l + ROWS * XPITCH;                 // 32*68 halves

    const int tid = threadIdx.x;
    const int b = blockIdx.x & 31, part = blockIdx.x >> 5;
    const int r0 = part * ROWS;
    const int lane = tid & 63, wv = tid >> 6;

    // ---- scales from k1's sumsq ----
    if (tid < 64) {
        ssc[tid] = 1.0f / fmaxf(sqrtf(sumsq[b * 64 + tid]), 1e-12f);
    } else if (tid < 128) {
        stc[tid - 64] = 1.0f / fmaxf(sqrtf(sumsq[BSZ * 64 + b * 64 + (tid - 64)]), 1e-12f);
    }
    for (int m = tid; m < MPITCH; m += 1024) v_l[m] = (m < NTOK) ? 0.f : -1000.f;
    __syncthreads();

    // ---- stage scaled xs rows (fp16) ----
    for (int idx = tid; idx < ROWS * 64; idx += 1024) {
        int r = idx >> 6, h = idx & 63;
        float v = __half2float(xsh[((size_t)b * NTOK + r0 + r) * 64 + h]) * ssc[h];
        xs_l[r * XPITCH + h] = __float2half(v);
    }
    __syncthreads();

    // ---- build Ms' slice: M = sum_h (xs-xt)^2, in 32-col chunks ----
    for (int c0 = 0; c0 < NTOK; c0 += 32) {
        for (int idx = tid; idx < 32 * 64; idx += 1024) {
            int m = idx >> 6, h = idx & 63;
            float v = __half2float(xth[((size_t)b * NTOK + c0 + m) * 64 + h]) * stc[h];
            xt_l[m * XPITCH + h] = __float2half(v);
        }
        __syncthreads();
        for (int idx = tid; idx < ROWS * 32; idx += 1024) {
            int r = idx >> 5, c = idx & 31;
            const __half2* xr = (const __half2*)(xs_l + r * XPITCH);
            const __half2* tr = (const __half2*)(xt_l + c * XPITCH);
            float a = 0.f;
#pragma unroll
            for (int h2 = 0; h2 < 32; h2++) {
                float2 av = __half22float2(xr[h2]);
                float2 tv = __half22float2(tr[h2]);
                float dx = av.x - tv.x, dy = av.y - tv.y;
                a = fmaf(dx, dx, a);
                a = fmaf(dy, dy, a);
            }
            Ms[r * MPITCH + c0 + c] = __float2half(a * MS_SCALE);
        }
        __syncthreads();
    }
    // pad columns 576..639 with -1000 (exp2 -> 0)
    for (int idx = tid; idx < ROWS * (MPITCH - NTOK); idx += 1024) {
        int r = idx >> 6, k = idx & 63;
        Ms[r * MPITCH + NTOK + k] = __float2half(-1000.f);
    }
    __syncthreads();

    int* cnt = counters + b * 16;
    const size_t Pb = (size_t)b * WGB * NTOK;
    const size_t Ppar = (size_t)BSZ * WGB * NTOK;

    for (int it = 1; it <= ITERS; ++it) {
        if (it > 1) {
            // combine v partials (XCD-local L2 reads)
            if (tid < NTOK) {
                const float* Pp = P + Ppar * ((it - 1) & 1) + Pb;
                float s = 0.f;
#pragma unroll
                for (int w = 0; w < WGB; w++) s += Pp[w * NTOK + tid];
                v_l[tid] = -LOG2_N - __builtin_amdgcn_logf(s);
            }
            __syncthreads();
        }
        // ---- u-pass: wave per row, v' cached in registers ----
        float2 vr[5];
#pragma unroll
        for (int j = 0; j < 5; j++) vr[j] = *(const float2*)&v_l[128 * j + 2 * lane];
        for (int r = wv; r < ROWS; r += 16) {
            const __half* row = Ms + r * MPITCH;
            float a = 0.f;
#pragma unroll
            for (int j = 0; j < 5; j++) {
                float2 f = __half22float2(*(const __half2*)&row[128 * j + 2 * lane]);
                a += __builtin_amdgcn_exp2f(f.x + vr[j].x);
                a += __builtin_amdgcn_exp2f(f.y + vr[j].y);
            }
#pragma unroll
            for (int off = 32; off > 0; off >>= 1) a += __shfl_xor(a, off, 64);
            if (lane == 0) u_l[r] = -LOG2_N - __builtin_amdgcn_logf(a);
        }
        __syncthreads();
        // ---- v-pass: thread owns a column pair over half the rows ----
        if (tid < NTOK) {
            int hf = tid / 288, p = tid - hf * 288;
            const __half* col = Ms + 2 * p;
            float a0 = 0.f, a1 = 0.f;
            int n1 = hf * 24;
#pragma unroll
            for (int nn = 0; nn < 24; nn++, n1++) {
                float uu = u_l[n1];
                float2 f = __half22float2(*(const __half2*)&col[n1 * MPITCH]);
                a0 += __builtin_amdgcn_exp2f(f.x + uu);
                a1 += __builtin_amdgcn_exp2f(f.y + uu);
            }
            ((float2*)vtmp)[hf * 288 + p] = make_float2(a0, a1);
        }
        __syncthreads();
        if (tid < NTOK) {
            float s = vtmp[tid] + vtmp[NTOK + tid];
            P[Ppar * (it & 1) + Pb + (size_t)part * NTOK + tid] = s;
        }
        // ---- per-batch device barrier (XCD-local counter) ----
        __syncthreads();
        if (tid == 0) {
            __threadfence();
            __hip_atomic_fetch_add(cnt, 1, __ATOMIC_RELEASE, __HIP_MEMORY_SCOPE_AGENT);
            const int target = WGB * it;
            while (__hip_atomic_load(cnt, __ATOMIC_RELAXED, __HIP_MEMORY_SCOPE_AGENT) < target)
                __builtin_amdgcn_s_sleep(1);
            __threadfence();
        }
        __syncthreads();
    }

    // ---- final: combine v(50), accumulate sum(T*M) over own slice ----
    if (tid < NTOK) {
        const float* Pp = P + Pb;  // iter 50 wrote parity 0
        float s = 0.f;
#pragma unroll
        for (int w = 0; w < WGB; w++) s += Pp[w * NTOK + tid];
        v_l[tid] = -LOG2_N - __builtin_amdgcn_logf(s);
    }
    __syncthreads();
    float acc = 0.f;
    for (int idx = tid; idx < ROWS * NTOK; idx += 1024) {
        int r = idx / NTOK, m = idx - r * NTOK;
        float msp = __half2float(Ms[r * MPITCH + m]);
        acc = fmaf(__builtin_amdgcn_exp2f(msp + u_l[r] + v_l[m]), msp, acc);
    }
#pragma unroll
    for (int off = 32; off > 0; off >>= 1) acc += __shfl_xor(acc, off, 64);
    if (lane == 0) red[wv] = acc;
    __syncthreads();
    if (tid == 0) {
        float s = 0.f;
#pragma unroll
        for (int w = 0; w < 16; w++) s += red[w];
        atomicAdd(gsum, s * M_FROM_MSP);
        __threadfence();
        int old = __hip_atomic_fetch_add(done, 1, __ATOMIC_ACQ_REL, __HIP_MEMORY_SCOPE_AGENT);
        if (old == NWG - 1) {
            __threadfence();
            out[0] = __hip_atomic_load(gsum, __ATOMIC_RELAXED, __HIP_MEMORY_SCOPE_AGENT)
                     * (1.0f / BSZ);
        }
    }
}

extern "C" void kernel_launch(void* const* d_in, const int* in_sizes, int n_in,
                              void* d_out, int out_size, void* d_ws, size_t ws_size,
                              hipStream_t stream) {
    const float* feat_s = (const float*)d_in[0];
    const float* feat_t = (const float*)d_in[1];
    const float* Ws = (const float*)d_in[2];
    const float* bs = (const float*)d_in[3];
    const float* Wt = (const float*)d_in[4];
    const float* bt = (const float*)d_in[5];

    char* ws = (char*)d_ws;
    int* counters = (int*)(ws + OFF_CNT);
    int* done     = (int*)(ws + OFF_DONE);
    float* gsum   = (float*)(ws + OFF_GSUM);
    float* sumsq  = (float*)(ws + OFF_SQS);
    float* P      = (float*)(ws + OFF_P);
    __half* xs    = (__half*)(ws + OFF_XS);
    __half* xt    = (__half*)(ws + OFF_XT);
    float* out = (float*)d_out;

    // zero barrier counters, done, gsum, sumsq (ws is poisoned 0xAA)
    hipMemsetAsync(ws, 0, MEMSET_BYTES, stream);

    hipLaunchKernelGGL(k1_proj, dim3(9, 32, 2), dim3(128), 0, stream,
                       feat_s, feat_t, Ws, bs, Wt, bt, xs, xt, sumsq);

    (void)hipFuncSetAttribute((const void*)k4_sinkhorn,
                              hipFuncAttributeMaxDynamicSharedMemorySize, SMEM_BYTES);
    hipLaunchKernelGGL(k4_sinkhorn, dim3(NWG), dim3(1024), SMEM_BYTES, stream,
                       xs, xt, sumsq, P, counters, done, gsum, out);
}

// Round 3
// 943.670 us; speedup vs baseline: 1.7697x; 1.7086x over previous
//
#include <hip/hip_runtime.h>
#include <hip/hip_fp16.h>

// Problem constants
#define BSZ 32
#define CS_ 640
#define CT_ 768
#define NTOK 576
#define HID 64
#define ITERS 50
#define WGB 16           // workgroups per batch
#define ROWS 36          // rows of M per workgroup (576/16)
#define NWG (BSZ*WGB)    // 512 wgs = exactly 2 per CU (uniform), 32 waves/CU
#define MPITCH 640       // halves per Ms row (576 real + 64 pad of -1000)
#define XPITCH 68        // halves per staged x row

#define LOG2_N 9.169925001442312f         // log2(576)
#define MS_SCALE 14.426950408889634f      // 10 * log2(e):  Ms' = M/reg * log2(e)
#define M_FROM_MSP 0.06931471805599453f   // ln2 / 10

// Workspace layout (bytes)
#define OFF_CNT 0              // 32 barrier counters, 64B apart (2048 B)
#define OFF_DONE 2048          // int
#define OFF_GSUM 2056          // float
#define OFF_DUMMY 2112         // 512 f32 (keep-alive sink)
#define OFF_SQS 4160           // sumsq [2][32][64] f32 (16384 B)
#define OFF_PACC 20544         // col-sum accumulators [2][32][576] f32 = 147456 B
#define MEMSET_BYTES 168000
#define OFF_XS 168000          // xs fp16 [32][576][64] = 2,359,296
#define OFF_XT 2527296         // xt fp16 [32][576][64] = 2,359,296 (end 4,886,592)

// LDS layout (bytes); total 61,056 -> 2 wgs/CU (122,112 <= 163,840)
#define L_MS 0                 // 36*640*2 = 46080
#define L_U 46080              // 36*4 = 144
#define L_V 46224              // 640*4 = 2560
#define L_RED 48784            // 16*4 = 64
#define L_UNION 48848          // iters: vtmp 576*2*4 = 4608
                               // build: ssc(256)+stc(256)+sqs(144)+sqt(2304)+xs_l(4896)+xt_l(4352)=12208
#define SMEM_BYTES 61056

// ---------------------------------------------------------------------------
// K1: projection + bias -> fp16 x, plus fused per-(b,h) sum-of-squares.
// ---------------------------------------------------------------------------
__global__ __launch_bounds__(128) void k1_proj(
    const float* __restrict__ feat_s, const float* __restrict__ feat_t,
    const float* __restrict__ Ws, const float* __restrict__ bs,
    const float* __restrict__ Wt, const float* __restrict__ bt,
    __half* __restrict__ xs, __half* __restrict__ xt, float* __restrict__ sumsq)
{
    const int nblk = blockIdx.x, b = blockIdx.y, st = blockIdx.z;
    const float* feat = st ? feat_t : feat_s;
    const float* W    = st ? Wt : Ws;
    const float* bias = st ? bt : bs;
    __half* out       = st ? xt : xs;
    const int C       = st ? CT_ : CS_;

    const int lane = threadIdx.x & 63;
    const int wv = __builtin_amdgcn_readfirstlane((int)(threadIdx.x >> 6));
    const int h0 = wv * 32;
    const int n = nblk * 64 + lane;

    float acc[32];
#pragma unroll
    for (int i = 0; i < 32; i++) acc[i] = 0.f;

    const float* fb = feat + (size_t)b * C * NTOK + n;
    for (int c0 = 0; c0 < C; c0 += 16) {
        float f[16];
#pragma unroll
        for (int j = 0; j < 16; j++) f[j] = fb[(size_t)(c0 + j) * NTOK];
#pragma unroll
        for (int hh = 0; hh < 32; hh++) {
            const float* wr = W + (size_t)(h0 + hh) * C + c0;
#pragma unroll
            for (int j = 0; j < 16; j++) acc[hh] = fmaf(f[j], wr[j], acc[hh]);
        }
    }
#pragma unroll
    for (int hh = 0; hh < 32; hh++) acc[hh] += bias[h0 + hh];

    __half2 hp[16];
#pragma unroll
    for (int hh = 0; hh < 32; hh += 2)
        hp[hh >> 1] = __floats2half2_rn(acc[hh], acc[hh + 1]);
    float4* op = (float4*)(out + ((size_t)b * NTOK + n) * HID + h0);
#pragma unroll
    for (int q = 0; q < 4; q++) op[q] = ((const float4*)hp)[q];

    float* sq = sumsq + (size_t)st * (BSZ * 64) + b * 64 + h0;
#pragma unroll
    for (int hh = 0; hh < 32; hh++) {
        float v2 = acc[hh] * acc[hh];
#pragma unroll
        for (int off = 32; off > 0; off >>= 1) v2 += __shfl_xor(v2, off, 64);
        if (lane == 0) atomicAdd(sq + hh, v2);
    }
}

// ---------------------------------------------------------------------------
// K4: persistent Sinkhorn, fence-free. 512 wgs = 16/batch (36 rows each).
// All cross-wg data moves via RELAXED agent-scope atomics (execute at LLC,
// no L2 writeback/invalidate). Returning atomics + pre-barrier vmcnt drain
// give completion ordering; counter add after __syncthreads gives release.
// Accumulator "zeroing" = owner re-adds -s_kept (adds commute).
// ---------------------------------------------------------------------------
__global__ __launch_bounds__(1024, 8) void k4_sinkhorn(
    const __half* __restrict__ xsh, const __half* __restrict__ xth,
    const float* __restrict__ sumsq, float* __restrict__ Pacc,
    int* __restrict__ counters, int* __restrict__ done,
    float* __restrict__ gsum, float* __restrict__ dummyout,
    float* __restrict__ out)
{
    extern __shared__ char smem[];
    __half* Ms  = (__half*)(smem + L_MS);
    float* u_l  = (float*)(smem + L_U);
    float* v_l  = (float*)(smem + L_V);
    float* red  = (float*)(smem + L_RED);
    float* vtmp = (float*)(smem + L_UNION);               // iter phase
    float* ssc  = (float*)(smem + L_UNION);               // build phase (aliases vtmp)
    float* stc  = (float*)(smem + L_UNION + 256);
    float* sqs  = (float*)(smem + L_UNION + 512);
    float* sqt  = (float*)(smem + L_UNION + 656);
    __half* xs_l = (__half*)(smem + L_UNION + 2960);      // 36*68 halves
    __half* xt_l = (__half*)(smem + L_UNION + 7856);      // 32*68 halves

    const int tid = threadIdx.x;
    const int b = blockIdx.x & 31, part = blockIdx.x >> 5;
    const int r0 = part * ROWS;
    const int lane = tid & 63, wv = tid >> 6;
    float dummy = 0.f;    // consumes atomic returns (keeps sc0 => vmcnt completion)
    float s_kept = 0.f;   // owner's remembered accumulator value (for -s zeroing)

    // ---- scales ----
    if (tid < 64) {
        ssc[tid] = 1.0f / fmaxf(sqrtf(sumsq[b * 64 + tid]), 1e-12f);
    } else if (tid < 128) {
        stc[tid - 64] = 1.0f / fmaxf(sqrtf(sumsq[BSZ * 64 + b * 64 + (tid - 64)]), 1e-12f);
    }
    for (int m = tid; m < MPITCH; m += 1024) v_l[m] = (m < NTOK) ? 0.f : -1000.f;
    __syncthreads();

    // ---- stage scaled xs slice (fp16); sqt for all 576 target tokens ----
    for (int idx = tid; idx < ROWS * 64; idx += 1024) {
        int r = idx >> 6, h = idx & 63;
        xs_l[r * XPITCH + h] =
            __float2half(__half2float(xsh[((size_t)b * NTOK + r0 + r) * 64 + h]) * ssc[h]);
    }
    if (tid < NTOK) {
        const __half* tp = xth + ((size_t)b * NTOK + tid) * 64;
        float s = 0.f;
#pragma unroll
        for (int h = 0; h < 64; h++) { float v = __half2float(tp[h]) * stc[h]; s = fmaf(v, v, s); }
        sqt[tid] = s;
    }
    __syncthreads();
    if (tid < ROWS) {
        float s = 0.f;
#pragma unroll
        for (int h = 0; h < 64; h++) { float v = __half2float(xs_l[tid * XPITCH + h]); s = fmaf(v, v, s); }
        sqs[tid] = s;
    }

    // ---- build Ms' slice: M = sqs + sqt - 2*dot, 18 chunks of 32 cols ----
    for (int c0 = 0; c0 < NTOK; c0 += 32) {
        __syncthreads();   // xt_l reuse + (first pass) sqs/sqt ready
        for (int idx = tid; idx < 32 * 64; idx += 1024) {
            int m = idx >> 6, h = idx & 63;
            xt_l[m * XPITCH + h] =
                __float2half(__half2float(xth[((size_t)b * NTOK + c0 + m) * 64 + h]) * stc[h]);
        }
        __syncthreads();
        for (int idx = tid; idx < ROWS * 32; idx += 1024) {
            int r = idx >> 5, c = idx & 31;
            const __half2* xr = (const __half2*)(xs_l + r * XPITCH);
            const __half2* tr = (const __half2*)(xt_l + c * XPITCH);
            float d = 0.f;
#pragma unroll
            for (int h2 = 0; h2 < 32; h2++) {
                float2 av = __half22float2(xr[h2]);
                float2 tv = __half22float2(tr[h2]);
                d = fmaf(av.x, tv.x, d);
                d = fmaf(av.y, tv.y, d);
            }
            float M = fmaxf(sqs[r] + sqt[c] - 2.f * d, 0.f);
            Ms[r * MPITCH + c0 + c] = __float2half(M * MS_SCALE);
        }
    }
    __syncthreads();
    for (int idx = tid; idx < ROWS * (MPITCH - NTOK); idx += 1024) {
        int r = idx >> 6, k = idx & 63;
        Ms[r * MPITCH + NTOK + k] = __float2half(-1000.f);
    }
    __syncthreads();

    int* cnt = counters + b * 16;

    for (int it = 1; it <= ITERS; ++it) {
        if (it > 1) {
            // combine: one RELAXED atomic load per column (bypasses stale L1/L2);
            // owner also re-adds -s_kept into the OTHER parity (commutative zeroing)
            if (tid < NTOK) {
                const int qr = (it - 1) & 1, qw = it & 1;
                float s = __hip_atomic_load(&Pacc[(size_t)(qr * BSZ + b) * NTOK + tid],
                                            __ATOMIC_RELAXED, __HIP_MEMORY_SCOPE_AGENT);
                v_l[tid] = -LOG2_N - __builtin_amdgcn_logf(s);
                if (tid >= r0 && tid < r0 + ROWS) {
                    if (s_kept != 0.f)
                        dummy += __hip_atomic_fetch_add(
                            &Pacc[(size_t)(qw * BSZ + b) * NTOK + tid], -s_kept,
                            __ATOMIC_RELAXED, __HIP_MEMORY_SCOPE_AGENT);
                    s_kept = s;
                }
            }
            __syncthreads();
        }
        // ---- u-pass: wave per row, v' cached in registers ----
        float2 vr[5];
#pragma unroll
        for (int j = 0; j < 5; j++) vr[j] = *(const float2*)&v_l[128 * j + 2 * lane];
        for (int r = wv; r < ROWS; r += 16) {
            const __half* row = Ms + r * MPITCH;
            float a = 0.f;
#pragma unroll
            for (int j = 0; j < 5; j++) {
                float2 f = __half22float2(*(const __half2*)&row[128 * j + 2 * lane]);
                a += __builtin_amdgcn_exp2f(f.x + vr[j].x);
                a += __builtin_amdgcn_exp2f(f.y + vr[j].y);
            }
#pragma unroll
            for (int off = 32; off > 0; off >>= 1) a += __shfl_xor(a, off, 64);
            if (lane == 0) u_l[r] = -LOG2_N - __builtin_amdgcn_logf(a);
        }
        __syncthreads();
        // ---- v-pass: thread owns a column pair over half the rows ----
        if (tid < NTOK) {
            int hf = tid / 288, p = tid - hf * 288;
            const __half* col = Ms + 2 * p;
            float a0 = 0.f, a1 = 0.f;
            int n1 = hf * 18;
#pragma unroll
            for (int nn = 0; nn < 18; nn++, n1++) {
                float uu = u_l[n1];
                float2 f = __half22float2(*(const __half2*)&col[n1 * MPITCH]);
                a0 += __builtin_amdgcn_exp2f(f.x + uu);
                a1 += __builtin_amdgcn_exp2f(f.y + uu);
            }
            ((float2*)vtmp)[hf * 288 + p] = make_float2(a0, a1);
        }
        __syncthreads();
        if (tid < NTOK) {
            float s = vtmp[tid] + vtmp[NTOK + tid];
            dummy += __hip_atomic_fetch_add(&Pacc[(size_t)((it & 1) * BSZ + b) * NTOK + tid], s,
                                            __ATOMIC_RELAXED, __HIP_MEMORY_SCOPE_AGENT);
        }
        // ---- per-batch barrier: relaxed counter; syncthreads' vmcnt(0) drain
        //      orders it after the (returning) P-adds ----
        __syncthreads();
        if (tid == 0) {
            __hip_atomic_fetch_add(cnt, 1, __ATOMIC_RELAXED, __HIP_MEMORY_SCOPE_AGENT);
            const int target = WGB * it;
            while (__hip_atomic_load(cnt, __ATOMIC_RELAXED, __HIP_MEMORY_SCOPE_AGENT) < target)
                __builtin_amdgcn_s_sleep(1);
        }
        __syncthreads();
    }

    // ---- final: v(50) from parity 0; accumulate sum(T*M) over own slice ----
    if (tid < NTOK) {
        float s = __hip_atomic_load(&Pacc[(size_t)b * NTOK + tid],
                                    __ATOMIC_RELAXED, __HIP_MEMORY_SCOPE_AGENT);
        v_l[tid] = -LOG2_N - __builtin_amdgcn_logf(s);
    }
    __syncthreads();
    float acc = 0.f;
    for (int idx = tid; idx < ROWS * NTOK; idx += 1024) {
        int r = idx / NTOK, m = idx - r * NTOK;
        float msp = __half2float(Ms[r * MPITCH + m]);
        acc = fmaf(__builtin_amdgcn_exp2f(msp + u_l[r] + v_l[m]), msp, acc);
    }
#pragma unroll
    for (int off = 32; off > 0; off >>= 1) acc += __shfl_xor(acc, off, 64);
    if (lane == 0) red[wv] = acc;
    __syncthreads();
    if (tid == 0) {
        float s = 0.f;
#pragma unroll
        for (int w = 0; w < 16; w++) s += red[w];
        float old = __hip_atomic_fetch_add(gsum, s * M_FROM_MSP,
                                           __ATOMIC_RELAXED, __HIP_MEMORY_SCOPE_AGENT);
        // data-dependence: done-add address depends on gsum return -> HW must
        // complete the gsum add before issuing the done add (no fence needed)
        int* dptr = done + ((old == -1.2345678e33f) ? 1 : 0);
        int prev = __hip_atomic_fetch_add(dptr, 1, __ATOMIC_RELAXED, __HIP_MEMORY_SCOPE_AGENT);
        if (prev == NWG - 1) {
            float tot = __hip_atomic_load(gsum, __ATOMIC_RELAXED, __HIP_MEMORY_SCOPE_AGENT);
            out[0] = tot * (1.0f / BSZ);
        }
    }
    // keep `dummy` (and thus the returning forms of all atomics) alive
    if (dummy == -1.2345678e33f) dummyout[blockIdx.x] = 1.f;
}

extern "C" void kernel_launch(void* const* d_in, const int* in_sizes, int n_in,
                              void* d_out, int out_size, void* d_ws, size_t ws_size,
                              hipStream_t stream) {
    const float* feat_s = (const float*)d_in[0];
    const float* feat_t = (const float*)d_in[1];
    const float* Ws = (const float*)d_in[2];
    const float* bs = (const float*)d_in[3];
    const float* Wt = (const float*)d_in[4];
    const float* bt = (const float*)d_in[5];

    char* ws = (char*)d_ws;
    int* counters  = (int*)(ws + OFF_CNT);
    int* done      = (int*)(ws + OFF_DONE);
    float* gsum    = (float*)(ws + OFF_GSUM);
    float* dummyo  = (float*)(ws + OFF_DUMMY);
    float* sumsq   = (float*)(ws + OFF_SQS);
    float* Pacc    = (float*)(ws + OFF_PACC);
    __half* xs     = (__half*)(ws + OFF_XS);
    __half* xt     = (__half*)(ws + OFF_XT);
    float* out = (float*)d_out;

    // zero counters, done, gsum, sumsq, Pacc (ws is poisoned 0xAA)
    hipMemsetAsync(ws, 0, MEMSET_BYTES, stream);

    hipLaunchKernelGGL(k1_proj, dim3(9, 32, 2), dim3(128), 0, stream,
                       feat_s, feat_t, Ws, bs, Wt, bt, xs, xt, sumsq);

    (void)hipFuncSetAttribute((const void*)k4_sinkhorn,
                              hipFuncAttributeMaxDynamicSharedMemorySize, SMEM_BYTES);
    hipLaunchKernelGGL(k4_sinkhorn, dim3(NWG), dim3(1024), SMEM_BYTES, stream,
                       xs, xt, sumsq, Pacc, counters, done, gsum, dummyo, out);
}

// Round 4
// 628.383 us; speedup vs baseline: 2.6577x; 1.5017x over previous
//
#include <hip/hip_runtime.h>
#include <hip/hip_fp16.h>

// Problem constants
#define BSZ 32
#define CS_ 640
#define CT_ 768
#define NTOK 576
#define HID 64
#define ITERS 50
#define WGB 16           // workgroups per batch
#define ROWS 36          // rows of M per workgroup (576/16)
#define NWG (BSZ*WGB)    // 512 wgs = exactly 2 per CU (uniform), 32 waves/CU
#define MPITCH 640       // halves per Ms row (576 real + 64 pad of -1000)
#define XPITCH 68        // halves per staged x row

#define LOG2_N 9.169925001442312f         // log2(576)
#define MS_SCALE 14.426950408889634f      // 10 * log2(e):  Ms' = M/reg * log2(e)
#define M_FROM_MSP 0.06931471805599453f   // ln2 / 10

// Workspace layout (bytes)
#define OFF_CNT 0              // 32 barrier counters, 64B apart (2048 B)
#define OFF_DONE 2048          // int
#define OFF_GSUM 2056          // float
#define OFF_DUMMY 2112         // 512 f32 (keep-alive sink)
#define OFF_SQS 4160           // sumsq [2][32][64] f32 (16384 B)
#define OFF_PACC 20544         // col-sum accumulators [2][32][576] f32 = 147456 B
#define MEMSET_BYTES 168000
#define OFF_XS 168000          // xs fp16 [32][576][64] = 2,359,296
#define OFF_XT 2527296         // xt fp16 [32][576][64] = 2,359,296 (end 4,886,592)

// k4 LDS layout (bytes); total 61,056 -> 2 wgs/CU (122,112 <= 163,840)
#define L_MS 0                 // 36*640*2 = 46080
#define L_U 46080              // 36*4 = 144
#define L_V 46224              // 640*4 = 2560
#define L_RED 48784            // 16*4 = 64
#define L_UNION 48848          // iters: vtmp 576*2*4 = 4608
                               // build: ssc(256)+stc(256)+sqs(144)+sqt(2304)+xs_l(4896)+xt_l(4352)
#define SMEM_BYTES 61056

// ---------------------------------------------------------------------------
// K1 (rebuilt): LDS-staged projection GEMM.
// Block = 512 threads (8 waves) owns one 64-token tile of one (batch, side).
// K-loop: stage 64c x 64tok fp32 chunk to LDS (coalesced in, conflict-free
// out), each wave computes 8 h with wave-uniform (scalar) W reads.
// Fused: bias, fp16 x write, per-(b,h) token sum-of-squares (atomicAdd).
// ---------------------------------------------------------------------------
template <int C>
__device__ __forceinline__ void proj_body(
    const float* __restrict__ feat,   // [C][576] this batch
    const float* __restrict__ W,      // [64][C]
    const float* __restrict__ bias,   // [64]
    __half* __restrict__ out,         // [576][64] this batch
    float* __restrict__ sq,           // [64] this (side,batch)
    float (*fbuf)[64], int nblk)
{
    const int tid = threadIdx.x;
    const int lane = tid & 63;
    const int wv = __builtin_amdgcn_readfirstlane((int)(tid >> 6));
    const int h0 = wv * 8;
    const int n0 = nblk * 64;

    float acc[8];
#pragma unroll
    for (int i = 0; i < 8; i++) acc[i] = 0.f;

    const float* wbase = W + (size_t)h0 * C;
    for (int k = 0; k < (C >> 6); k++) {
        const int c0 = k << 6;
        __syncthreads();   // fbuf reuse
#pragma unroll
        for (int j = 0; j < 8; j++) {
            int idx = tid + j * 512;
            int cl = idx >> 6, tok = idx & 63;
            fbuf[cl][tok] = feat[(size_t)(c0 + cl) * NTOK + n0 + tok];
        }
        __syncthreads();
#pragma unroll 2
        for (int cc8 = 0; cc8 < 64; cc8 += 8) {
            float f[8];
#pragma unroll
            for (int j = 0; j < 8; j++) f[j] = fbuf[cc8 + j][lane];
#pragma unroll
            for (int hh = 0; hh < 8; hh++) {
                const float* wr = wbase + (size_t)hh * C + c0 + cc8;
#pragma unroll
                for (int j = 0; j < 8; j++) acc[hh] = fmaf(f[j], wr[j], acc[hh]);
            }
        }
    }
#pragma unroll
    for (int hh = 0; hh < 8; hh++) acc[hh] += bias[h0 + hh];

    __half2 hp[4];
#pragma unroll
    for (int hh = 0; hh < 8; hh += 2) hp[hh >> 1] = __floats2half2_rn(acc[hh], acc[hh + 1]);
    *(float4*)(out + (size_t)(n0 + lane) * HID + h0) = *(const float4*)hp;

#pragma unroll
    for (int hh = 0; hh < 8; hh++) {
        float v2 = acc[hh] * acc[hh];
#pragma unroll
        for (int off = 32; off > 0; off >>= 1) v2 += __shfl_xor(v2, off, 64);
        if (lane == 0) atomicAdd(sq + h0 + hh, v2);
    }
}

__global__ __launch_bounds__(512, 4) void k1_proj(
    const float* __restrict__ feat_s, const float* __restrict__ feat_t,
    const float* __restrict__ Ws, const float* __restrict__ bs,
    const float* __restrict__ Wt, const float* __restrict__ bt,
    __half* __restrict__ xs, __half* __restrict__ xt, float* __restrict__ sumsq)
{
    __shared__ float fbuf[64][64];
    const int nblk = blockIdx.x, b = blockIdx.y, st = blockIdx.z;
    if (st == 0) {
        proj_body<CS_>(feat_s + (size_t)b * CS_ * NTOK, Ws, bs,
                       xs + (size_t)b * NTOK * HID, sumsq + b * 64, fbuf, nblk);
    } else {
        proj_body<CT_>(feat_t + (size_t)b * CT_ * NTOK, Wt, bt,
                       xt + (size_t)b * NTOK * HID, sumsq + (BSZ + b) * 64, fbuf, nblk);
    }
}

// ---------------------------------------------------------------------------
// K4: persistent Sinkhorn, fence-free (unchanged from round 3).
// ---------------------------------------------------------------------------
__global__ __launch_bounds__(1024, 8) void k4_sinkhorn(
    const __half* __restrict__ xsh, const __half* __restrict__ xth,
    const float* __restrict__ sumsq, float* __restrict__ Pacc,
    int* __restrict__ counters, int* __restrict__ done,
    float* __restrict__ gsum, float* __restrict__ dummyout,
    float* __restrict__ out)
{
    extern __shared__ char smem[];
    __half* Ms  = (__half*)(smem + L_MS);
    float* u_l  = (float*)(smem + L_U);
    float* v_l  = (float*)(smem + L_V);
    float* red  = (float*)(smem + L_RED);
    float* vtmp = (float*)(smem + L_UNION);
    float* ssc  = (float*)(smem + L_UNION);
    float* stc  = (float*)(smem + L_UNION + 256);
    float* sqs  = (float*)(smem + L_UNION + 512);
    float* sqt  = (float*)(smem + L_UNION + 656);
    __half* xs_l = (__half*)(smem + L_UNION + 2960);
    __half* xt_l = (__half*)(smem + L_UNION + 7856);

    const int tid = threadIdx.x;
    const int b = blockIdx.x & 31, part = blockIdx.x >> 5;
    const int r0 = part * ROWS;
    const int lane = tid & 63, wv = tid >> 6;
    float dummy = 0.f;
    float s_kept = 0.f;

    if (tid < 64) {
        ssc[tid] = 1.0f / fmaxf(sqrtf(sumsq[b * 64 + tid]), 1e-12f);
    } else if (tid < 128) {
        stc[tid - 64] = 1.0f / fmaxf(sqrtf(sumsq[BSZ * 64 + b * 64 + (tid - 64)]), 1e-12f);
    }
    for (int m = tid; m < MPITCH; m += 1024) v_l[m] = (m < NTOK) ? 0.f : -1000.f;
    __syncthreads();

    for (int idx = tid; idx < ROWS * 64; idx += 1024) {
        int r = idx >> 6, h = idx & 63;
        xs_l[r * XPITCH + h] =
            __float2half(__half2float(xsh[((size_t)b * NTOK + r0 + r) * 64 + h]) * ssc[h]);
    }
    if (tid < NTOK) {
        const __half* tp = xth + ((size_t)b * NTOK + tid) * 64;
        float s = 0.f;
#pragma unroll
        for (int h = 0; h < 64; h++) { float v = __half2float(tp[h]) * stc[h]; s = fmaf(v, v, s); }
        sqt[tid] = s;
    }
    __syncthreads();
    if (tid < ROWS) {
        float s = 0.f;
#pragma unroll
        for (int h = 0; h < 64; h++) { float v = __half2float(xs_l[tid * XPITCH + h]); s = fmaf(v, v, s); }
        sqs[tid] = s;
    }

    for (int c0 = 0; c0 < NTOK; c0 += 32) {
        __syncthreads();
        for (int idx = tid; idx < 32 * 64; idx += 1024) {
            int m = idx >> 6, h = idx & 63;
            xt_l[m * XPITCH + h] =
                __float2half(__half2float(xth[((size_t)b * NTOK + c0 + m) * 64 + h]) * stc[h]);
        }
        __syncthreads();
        for (int idx = tid; idx < ROWS * 32; idx += 1024) {
            int r = idx >> 5, c = idx & 31;
            const __half2* xr = (const __half2*)(xs_l + r * XPITCH);
            const __half2* tr = (const __half2*)(xt_l + c * XPITCH);
            float d = 0.f;
#pragma unroll
            for (int h2 = 0; h2 < 32; h2++) {
                float2 av = __half22float2(xr[h2]);
                float2 tv = __half22float2(tr[h2]);
                d = fmaf(av.x, tv.x, d);
                d = fmaf(av.y, tv.y, d);
            }
            float M = fmaxf(sqs[r] + sqt[c] - 2.f * d, 0.f);
            Ms[r * MPITCH + c0 + c] = __float2half(M * MS_SCALE);
        }
    }
    __syncthreads();
    for (int idx = tid; idx < ROWS * (MPITCH - NTOK); idx += 1024) {
        int r = idx >> 6, k = idx & 63;
        Ms[r * MPITCH + NTOK + k] = __float2half(-1000.f);
    }
    __syncthreads();

    int* cnt = counters + b * 16;

    for (int it = 1; it <= ITERS; ++it) {
        if (it > 1) {
            if (tid < NTOK) {
                const int qr = (it - 1) & 1, qw = it & 1;
                float s = __hip_atomic_load(&Pacc[(size_t)(qr * BSZ + b) * NTOK + tid],
                                            __ATOMIC_RELAXED, __HIP_MEMORY_SCOPE_AGENT);
                v_l[tid] = -LOG2_N - __builtin_amdgcn_logf(s);
                if (tid >= r0 && tid < r0 + ROWS) {
                    if (s_kept != 0.f)
                        dummy += __hip_atomic_fetch_add(
                            &Pacc[(size_t)(qw * BSZ + b) * NTOK + tid], -s_kept,
                            __ATOMIC_RELAXED, __HIP_MEMORY_SCOPE_AGENT);
                    s_kept = s;
                }
            }
            __syncthreads();
        }
        float2 vr[5];
#pragma unroll
        for (int j = 0; j < 5; j++) vr[j] = *(const float2*)&v_l[128 * j + 2 * lane];
        for (int r = wv; r < ROWS; r += 16) {
            const __half* row = Ms + r * MPITCH;
            float a = 0.f;
#pragma unroll
            for (int j = 0; j < 5; j++) {
                float2 f = __half22float2(*(const __half2*)&row[128 * j + 2 * lane]);
                a += __builtin_amdgcn_exp2f(f.x + vr[j].x);
                a += __builtin_amdgcn_exp2f(f.y + vr[j].y);
            }
#pragma unroll
            for (int off = 32; off > 0; off >>= 1) a += __shfl_xor(a, off, 64);
            if (lane == 0) u_l[r] = -LOG2_N - __builtin_amdgcn_logf(a);
        }
        __syncthreads();
        if (tid < NTOK) {
            int hf = tid / 288, p = tid - hf * 288;
            const __half* col = Ms + 2 * p;
            float a0 = 0.f, a1 = 0.f;
            int n1 = hf * 18;
#pragma unroll
            for (int nn = 0; nn < 18; nn++, n1++) {
                float uu = u_l[n1];
                float2 f = __half22float2(*(const __half2*)&col[n1 * MPITCH]);
                a0 += __builtin_amdgcn_exp2f(f.x + uu);
                a1 += __builtin_amdgcn_exp2f(f.y + uu);
            }
            ((float2*)vtmp)[hf * 288 + p] = make_float2(a0, a1);
        }
        __syncthreads();
        if (tid < NTOK) {
            float s = vtmp[tid] + vtmp[NTOK + tid];
            dummy += __hip_atomic_fetch_add(&Pacc[(size_t)((it & 1) * BSZ + b) * NTOK + tid], s,
                                            __ATOMIC_RELAXED, __HIP_MEMORY_SCOPE_AGENT);
        }
        __syncthreads();
        if (tid == 0) {
            __hip_atomic_fetch_add(cnt, 1, __ATOMIC_RELAXED, __HIP_MEMORY_SCOPE_AGENT);
            const int target = WGB * it;
            while (__hip_atomic_load(cnt, __ATOMIC_RELAXED, __HIP_MEMORY_SCOPE_AGENT) < target)
                __builtin_amdgcn_s_sleep(1);
        }
        __syncthreads();
    }

    if (tid < NTOK) {
        float s = __hip_atomic_load(&Pacc[(size_t)b * NTOK + tid],
                                    __ATOMIC_RELAXED, __HIP_MEMORY_SCOPE_AGENT);
        v_l[tid] = -LOG2_N - __builtin_amdgcn_logf(s);
    }
    __syncthreads();
    float acc = 0.f;
    for (int idx = tid; idx < ROWS * NTOK; idx += 1024) {
        int r = idx / NTOK, m = idx - r * NTOK;
        float msp = __half2float(Ms[r * MPITCH + m]);
        acc = fmaf(__builtin_amdgcn_exp2f(msp + u_l[r] + v_l[m]), msp, acc);
    }
#pragma unroll
    for (int off = 32; off > 0; off >>= 1) acc += __shfl_xor(acc, off, 64);
    if (lane == 0) red[wv] = acc;
    __syncthreads();
    if (tid == 0) {
        float s = 0.f;
#pragma unroll
        for (int w = 0; w < 16; w++) s += red[w];
        float old = __hip_atomic_fetch_add(gsum, s * M_FROM_MSP,
                                           __ATOMIC_RELAXED, __HIP_MEMORY_SCOPE_AGENT);
        int* dptr = done + ((old == -1.2345678e33f) ? 1 : 0);
        int prev = __hip_atomic_fetch_add(dptr, 1, __ATOMIC_RELAXED, __HIP_MEMORY_SCOPE_AGENT);
        if (prev == NWG - 1) {
            float tot = __hip_atomic_load(gsum, __ATOMIC_RELAXED, __HIP_MEMORY_SCOPE_AGENT);
            out[0] = tot * (1.0f / BSZ);
        }
    }
    if (dummy == -1.2345678e33f) dummyout[blockIdx.x] = 1.f;
}

extern "C" void kernel_launch(void* const* d_in, const int* in_sizes, int n_in,
                              void* d_out, int out_size, void* d_ws, size_t ws_size,
                              hipStream_t stream) {
    const float* feat_s = (const float*)d_in[0];
    const float* feat_t = (const float*)d_in[1];
    const float* Ws = (const float*)d_in[2];
    const float* bs = (const float*)d_in[3];
    const float* Wt = (const float*)d_in[4];
    const float* bt = (const float*)d_in[5];

    char* ws = (char*)d_ws;
    int* counters  = (int*)(ws + OFF_CNT);
    int* done      = (int*)(ws + OFF_DONE);
    float* gsum    = (float*)(ws + OFF_GSUM);
    float* dummyo  = (float*)(ws + OFF_DUMMY);
    float* sumsq   = (float*)(ws + OFF_SQS);
    float* Pacc    = (float*)(ws + OFF_PACC);
    __half* xs     = (__half*)(ws + OFF_XS);
    __half* xt     = (__half*)(ws + OFF_XT);
    float* out = (float*)d_out;

    hipMemsetAsync(ws, 0, MEMSET_BYTES, stream);

    hipLaunchKernelGGL(k1_proj, dim3(9, 32, 2), dim3(512), 0, stream,
                       feat_s, feat_t, Ws, bs, Wt, bt, xs, xt, sumsq);

    (void)hipFuncSetAttribute((const void*)k4_sinkhorn,
                              hipFuncAttributeMaxDynamicSharedMemorySize, SMEM_BYTES);
    hipLaunchKernelGGL(k4_sinkhorn, dim3(NWG), dim3(1024), SMEM_BYTES, stream,
                       xs, xt, sumsq, Pacc, counters, done, gsum, dummyo, out);
}